// Round 1
// baseline (268.707 us; speedup 1.0000x reference)
//
#include <hip/hip_runtime.h>
#include <hip/hip_bf16.h>

#define NPIX 4096
#define CCH 64

typedef __attribute__((ext_vector_type(4))) float f32x4;
typedef __attribute__((ext_vector_type(8))) short short8;

__device__ inline short f2bf(float f) {
  unsigned u = __float_as_uint(f);
  u += 0x7FFF + ((u >> 16) & 1);   // round-to-nearest-even
  return (short)(u >> 16);
}

// ---------------- projection: q,k (D=8) and v (C=64) ----------------
// Qp, Kp: [B][N][8] bf16 ; Vt: [B][64][N] bf16 (channel-major)
__global__ __launch_bounds__(256) void proj_kernel(
    const float* __restrict__ x,
    const float* __restrict__ Wq, const float* __restrict__ bq,
    const float* __restrict__ Wk, const float* __restrict__ bk,
    const float* __restrict__ Wv, const float* __restrict__ bv,
    short* __restrict__ Qp, short* __restrict__ Kp, short* __restrict__ Vt)
{
  const int p = blockIdx.x * 256 + threadIdx.x;   // 0..16383 = B*N
  const int b = p >> 12;
  const int n = p & 4095;
  const float* xb = x + ((size_t)b << 18) + n;    // x[b][c][n], c stride = 4096

  float qa[8], ka[8], va[64];
#pragma unroll
  for (int d = 0; d < 8; ++d) { qa[d] = bq[d]; ka[d] = bk[d]; }
#pragma unroll
  for (int e = 0; e < 64; ++e) va[e] = bv[e];

  for (int c0 = 0; c0 < 64; c0 += 8) {
    float xv[8];
#pragma unroll
    for (int i = 0; i < 8; ++i) xv[i] = xb[(size_t)(c0 + i) << 12];
#pragma unroll
    for (int d = 0; d < 8; ++d) {
#pragma unroll
      for (int i = 0; i < 8; ++i) {
        qa[d] = fmaf(Wq[d * 64 + c0 + i], xv[i], qa[d]);   // uniform -> s_load
        ka[d] = fmaf(Wk[d * 64 + c0 + i], xv[i], ka[d]);
      }
    }
#pragma unroll
    for (int e = 0; e < 64; ++e) {
#pragma unroll
      for (int i = 0; i < 8; ++i)
        va[e] = fmaf(Wv[e * 64 + c0 + i], xv[i], va[e]);
    }
  }

  short8 qo, ko;
#pragma unroll
  for (int d = 0; d < 8; ++d) { qo[d] = f2bf(qa[d]); ko[d] = f2bf(ka[d]); }
  *(short8*)(Qp + (size_t)p * 8) = qo;
  *(short8*)(Kp + (size_t)p * 8) = ko;
#pragma unroll
  for (int e = 0; e < 64; ++e)
    Vt[((size_t)(b * 64 + e) << 12) + n] = f2bf(va[e]);
}

// ---------------- fused flash attention ----------------
// grid = B * (N/64) = 256 blocks, 256 threads (4 waves); wave w owns 16 queries.
__global__ __launch_bounds__(256) void attn_kernel(
    const short* __restrict__ Qp, const short* __restrict__ Kp,
    const short* __restrict__ Vt,
    const float* __restrict__ x, const float* __restrict__ gamma,
    float* __restrict__ out)
{
  __shared__ __align__(16) short kLds[64 * 8];       // [key][8]      1 KB
  __shared__ __align__(16) short vLds[64 * 72];      // [ch][72pad]   9 KB
  __shared__ __align__(16) short pLds[4][16 * 72];   // per-wave [q][72pad] 9 KB

  const int blk = blockIdx.x;
  const int b  = blk >> 6;
  const int q0 = (blk & 63) * 64;
  const int tid  = threadIdx.x;
  const int w    = tid >> 6;
  const int lane = tid & 63;
  const int lg   = lane >> 4;     // 16-lane group 0..3
  const int lr   = lane & 15;

  // A-operand Q fragment: lane row=lr(query), cols 8*lg..+7 (only lg==0 real, rest 0)
  short8 qfrag = {0,0,0,0,0,0,0,0};
  if (lg == 0)
    qfrag = *(const short8*)(Qp + (size_t)(b * NPIX + q0 + w * 16 + lr) * 8);

  const short8 zero8 = {0,0,0,0,0,0,0,0};
  const f32x4  zf    = {0.f, 0.f, 0.f, 0.f};

  f32x4 oacc[4] = {zf, zf, zf, zf};
  float m[4] = {-1e30f, -1e30f, -1e30f, -1e30f};
  float s[4] = {0.f, 0.f, 0.f, 0.f};

  for (int kb = 0; kb < NPIX; kb += 64) {
    __syncthreads();
    // stage K tile [64][8]
    if (tid < 64) {
      short8 kv = *(const short8*)(Kp + (size_t)(b * NPIX + kb + tid) * 8);
      *(short8*)&kLds[tid * 8] = kv;
    }
    // stage V tile: vLds[ch][key], 144B padded rows
    {
      const int ch = tid >> 2, seg = tid & 3;
      const short* src = Vt + ((size_t)(b * 64 + ch) << 12) + kb + seg * 16;
      short8 v0 = *(const short8*)src;
      short8 v1 = *(const short8*)(src + 8);
      *(short8*)&vLds[ch * 72 + seg * 16]     = v0;
      *(short8*)&vLds[ch * 72 + seg * 16 + 8] = v1;
    }
    __syncthreads();

    // QK^T: 4 key sub-tiles of 16.  D layout: lane holds q=4*lg+r, key=lr.
    f32x4 en[4];
#pragma unroll
    for (int t = 0; t < 4; ++t) {
      short8 kf = *(const short8*)&kLds[(t * 16 + lr) * 8];  // key row, broadcast over lg
      kf = (lg == 0) ? kf : zero8;
      en[t] = __builtin_amdgcn_mfma_f32_16x16x32_bf16(qfrag, kf, zf, 0, 0, 0);
    }

    // online softmax over the 64 keys (row q lives in 16 lanes of group lg, reg r)
    float tm[4];
#pragma unroll
    for (int r = 0; r < 4; ++r)
      tm[r] = fmaxf(fmaxf(en[0][r], en[1][r]), fmaxf(en[2][r], en[3][r]));
#pragma unroll
    for (int msk = 1; msk < 16; msk <<= 1) {
#pragma unroll
      for (int r = 0; r < 4; ++r)
        tm[r] = fmaxf(tm[r], __shfl_xor(tm[r], msk));
    }
    float mn[4], scale[4];
#pragma unroll
    for (int r = 0; r < 4; ++r) {
      mn[r] = fmaxf(m[r], tm[r]);
      scale[r] = __expf(m[r] - mn[r]);
      m[r] = mn[r];
    }
    float psum[4] = {0.f, 0.f, 0.f, 0.f};
#pragma unroll
    for (int t = 0; t < 4; ++t) {
#pragma unroll
      for (int r = 0; r < 4; ++r) {
        float pv = __expf(en[t][r] - mn[r]);
        psum[r] += pv;
        pLds[w][(lg * 4 + r) * 72 + t * 16 + lr] = f2bf(pv);  // P[q][key]
      }
    }
#pragma unroll
    for (int msk = 1; msk < 16; msk <<= 1) {
#pragma unroll
      for (int r = 0; r < 4; ++r)
        psum[r] += __shfl_xor(psum[r], msk);
    }
#pragma unroll
    for (int r = 0; r < 4; ++r) s[r] = s[r] * scale[r] + psum[r];
#pragma unroll
    for (int et = 0; et < 4; ++et) {
#pragma unroll
      for (int r = 0; r < 4; ++r) oacc[et][r] *= scale[r];
    }

    // PV: out[q][e] += P[q][j] * V[j][e]; A = P (from pLds), B = Vt columns
#pragma unroll
    for (int kk = 0; kk < 2; ++kk) {
      short8 pf = *(const short8*)&pLds[w][lr * 72 + kk * 32 + lg * 8];
#pragma unroll
      for (int et = 0; et < 4; ++et) {
        short8 vf = *(const short8*)&vLds[(et * 16 + lr) * 72 + kk * 32 + lg * 8];
        oacc[et] = __builtin_amdgcn_mfma_f32_16x16x32_bf16(pf, vf, oacc[et], 0, 0, 0);
      }
    }
  }

  // epilogue: out = gamma * (acc/s) + x   (D layout: e = et*16+lr, q = 4*lg+r)
  const float g = gamma[0];
  float inv[4];
#pragma unroll
  for (int r = 0; r < 4; ++r) inv[r] = 1.0f / s[r];
#pragma unroll
  for (int et = 0; et < 4; ++et) {
    const int e = et * 16 + lr;
#pragma unroll
    for (int r = 0; r < 4; ++r) {
      const int q = q0 + w * 16 + lg * 4 + r;
      const size_t idx = ((size_t)(b * 64 + e) << 12) + q;
      out[idx] = fmaf(g, oacc[et][r] * inv[r], x[idx]);
    }
  }
}

extern "C" void kernel_launch(void* const* d_in, const int* in_sizes, int n_in,
                              void* d_out, int out_size, void* d_ws, size_t ws_size,
                              hipStream_t stream) {
  const float* x     = (const float*)d_in[0];
  const float* Wq    = (const float*)d_in[1];
  const float* bq    = (const float*)d_in[2];
  const float* Wk    = (const float*)d_in[3];
  const float* bk    = (const float*)d_in[4];
  const float* Wv    = (const float*)d_in[5];
  const float* bv    = (const float*)d_in[6];
  const float* gamma = (const float*)d_in[7];
  float* out = (float*)d_out;

  short* ws = (short*)d_ws;
  short* Qp = ws;                       // 4*4096*8  = 131072 halves
  short* Kp = ws + 131072;              // 131072 halves
  short* Vt = ws + 262144;              // 4*64*4096 = 1048576 halves

  proj_kernel<<<64, 256, 0, stream>>>(x, Wq, bq, Wk, bk, Wv, bv, Qp, Kp, Vt);
  attn_kernel<<<256, 256, 0, stream>>>(Qp, Kp, Vt, x, gamma, out);
}

// Round 2
// 157.410 us; speedup vs baseline: 1.7071x; 1.7071x over previous
//
#include <hip/hip_runtime.h>
#include <hip/hip_bf16.h>

#define NPIX 4096

typedef __attribute__((ext_vector_type(16))) float f32x16;
typedef __attribute__((ext_vector_type(8))) short short8;

__device__ inline short f2bf(float f) {   // round-to-nearest-even
  unsigned u = __float_as_uint(f);
  u += 0x7FFF + ((u >> 16) & 1);
  return (short)(u >> 16);
}
// truncating bf16 pair pack (softmax weights: 0.4% quantization, same as bf16 storage)
__device__ inline unsigned packbf2(float lo, float hi) {
  return (__float_as_uint(hi) & 0xFFFF0000u) | (__float_as_uint(lo) >> 16);
}

// ---------------- projection ----------------
// 5 waves/block: wave 0 -> q(8)+k(8); waves 1-4 -> v channels 16(w-1)..+15.
// lane = pixel. Qp,Kp: [B*N][8] bf16 ; Vt: [B*64][N] bf16.
__global__ __launch_bounds__(320) void proj_kernel(
    const float* __restrict__ x,
    const float* __restrict__ Wq, const float* __restrict__ bq,
    const float* __restrict__ Wk, const float* __restrict__ bk,
    const float* __restrict__ Wv, const float* __restrict__ bv,
    short* __restrict__ Qp, short* __restrict__ Kp, short* __restrict__ Vt)
{
  const int w    = threadIdx.x >> 6;
  const int lane = threadIdx.x & 63;
  const int p = blockIdx.x * 64 + lane;      // 0..16383
  const int b = p >> 12, n = p & 4095;
  const float* xb = x + ((size_t)b << 18) + n;

  float xv[64];
#pragma unroll
  for (int c = 0; c < 64; ++c) xv[c] = xb[(size_t)c << 12];

  if (w == 0) {
    float qa[8], ka[8];
#pragma unroll
    for (int d = 0; d < 8; ++d) {
      float aq = bq[d], ak = bk[d];
#pragma unroll
      for (int c = 0; c < 64; ++c) {
        aq = fmaf(Wq[d * 64 + c], xv[c], aq);   // uniform -> s_load, contiguous rows
        ak = fmaf(Wk[d * 64 + c], xv[c], ak);
      }
      qa[d] = aq; ka[d] = ak;
    }
    short8 qo, ko;
#pragma unroll
    for (int d = 0; d < 8; ++d) { qo[d] = f2bf(qa[d]); ko[d] = f2bf(ka[d]); }
    *(short8*)(Qp + (size_t)p * 8) = qo;
    *(short8*)(Kp + (size_t)p * 8) = ko;
  } else {
    const int e0 = (w - 1) * 16;
#pragma unroll
    for (int i = 0; i < 16; ++i) {
      float a = bv[e0 + i];
#pragma unroll
      for (int c = 0; c < 64; ++c) a = fmaf(Wv[(e0 + i) * 64 + c], xv[c], a);
      Vt[((size_t)(b * 64 + e0 + i) << 12) + n] = f2bf(a);
    }
  }
}

// ---------------- fused flash attention, no-max softmax ----------------
// grid = 256 (4 batches x 64 q-groups of 64). block = 512 thr = 8 waves.
// wave wv: all 64 queries of the group over keys [wv*512, wv*512+512).
// Swapped QK^T (mfma(K,Q)): lane holds 16 keys for query q=lane&31 (+32 for half 1).
// No LDS / no barriers in main loop; LDS atomic combine at the end.
__global__ __launch_bounds__(512, 2) void attn_kernel(
    const short* __restrict__ Qp, const short* __restrict__ Kp,
    const short* __restrict__ Vt,
    const float* __restrict__ x, const float* __restrict__ gamma,
    float* __restrict__ out)
{
  __shared__ float accLds[64][65];   // [q][e], +1 pad: conflict-free adds & reads
  __shared__ float sLds[64];

  const int tid  = threadIdx.x;
  const int wv   = tid >> 6;         // key split 0..7
  const int lane = tid & 63;
  const int lo   = lane & 31;
  const int hi   = lane >> 5;

  const int b  = blockIdx.x >> 6;
  const int q0 = (blockIdx.x & 63) * 64;

  for (int i = tid; i < 64 * 65; i += 512) (&accLds[0][0])[i] = 0.f;
  if (tid < 64) sLds[tid] = 0.f;
  __syncthreads();

  // Q B-fragments: lane col=q=lo, k-elems = channels 8*hi.. (hi=1 -> zero pad)
  short8 qf0 = {}, qf1 = {};
  if (hi == 0) {
    qf0 = *(const short8*)(Qp + (size_t)((b << 12) + q0 + lo) * 8);
    qf1 = *(const short8*)(Qp + (size_t)((b << 12) + q0 + 32 + lo) * 8);
  }

  const short* kbase = Kp + ((size_t)b << 12) * 8;
  const short* vbase = Vt + ((size_t)(b * 64) << 12);
  const int kb0 = wv * 512;

  // K A-fragment: lane row=key=lo, k=channels 8*hi.. ; hi half holds duplicate
  // garbage channels — harmless because Q's hi half is zero.
  short8 kf = *(const short8*)(kbase + (size_t)(kb0 + lo) * 8);

  f32x16 acc00 = {}, acc01 = {}, acc10 = {}, acc11 = {};  // [qhalf][etile]
  float psum0 = 0.f, psum1 = 0.f;

  for (int t = 0; t < 16; ++t) {
    const int kb = kb0 + t * 32;
    // prefetch next K tile (t=15 overreads into ws scratch — unused, in-bounds)
    short8 kfn = *(const short8*)(kbase + (size_t)(kb + 32 + lo) * 8);

    // V B-fragments: lane col=e, k-elems = keys kb+16c+8*hi..  (c=chunk, et=e-tile)
    const short* vp = vbase + ((size_t)lo << 12) + kb + 8 * hi;
    short8 vb00 = *(const short8*)(vp);                       // c0, e 0..31
    short8 vb10 = *(const short8*)(vp + 16);                  // c1, e 0..31
    short8 vb01 = *(const short8*)(vp + ((size_t)32 << 12));  // c0, e 32..63
    short8 vb11 = *(const short8*)(vp + ((size_t)32 << 12) + 16);

    const f32x16 z = {};
    f32x16 en0 = __builtin_amdgcn_mfma_f32_32x32x16_bf16(kf, qf0, z, 0, 0, 0);
    f32x16 en1 = __builtin_amdgcn_mfma_f32_32x32x16_bf16(kf, qf1, z, 0, 0, 0);

    // ---- q-half 0: weights, pack, cross-half swap, PV ----
    float p0[16];
#pragma unroll
    for (int i = 0; i < 16; ++i) p0[i] = __expf(fminf((float)en0[i], 70.f));
#pragma unroll
    for (int i = 0; i < 16; ++i) psum0 += p0[i];
    unsigned D0[8], E0[8];
#pragma unroll
    for (int j = 0; j < 8; ++j) D0[j] = packbf2(p0[2 * j], p0[2 * j + 1]);
#pragma unroll
    for (int j = 0; j < 8; ++j) E0[j] = (unsigned)__shfl_xor((int)D0[j], 32);
    union { unsigned u[4]; short8 s; } a0, a1;
    a0.u[0] = hi ? E0[2] : D0[0];  a0.u[1] = hi ? E0[3] : D0[1];
    a0.u[2] = hi ? D0[2] : E0[0];  a0.u[3] = hi ? D0[3] : E0[1];
    a1.u[0] = hi ? E0[6] : D0[4];  a1.u[1] = hi ? E0[7] : D0[5];
    a1.u[2] = hi ? D0[6] : E0[4];  a1.u[3] = hi ? D0[7] : E0[5];
    acc00 = __builtin_amdgcn_mfma_f32_32x32x16_bf16(a0.s, vb00, acc00, 0, 0, 0);
    acc01 = __builtin_amdgcn_mfma_f32_32x32x16_bf16(a0.s, vb01, acc01, 0, 0, 0);
    acc00 = __builtin_amdgcn_mfma_f32_32x32x16_bf16(a1.s, vb10, acc00, 0, 0, 0);
    acc01 = __builtin_amdgcn_mfma_f32_32x32x16_bf16(a1.s, vb11, acc01, 0, 0, 0);

    // ---- q-half 1 ----
    float p1[16];
#pragma unroll
    for (int i = 0; i < 16; ++i) p1[i] = __expf(fminf((float)en1[i], 70.f));
#pragma unroll
    for (int i = 0; i < 16; ++i) psum1 += p1[i];
    unsigned D1[8], E1[8];
#pragma unroll
    for (int j = 0; j < 8; ++j) D1[j] = packbf2(p1[2 * j], p1[2 * j + 1]);
#pragma unroll
    for (int j = 0; j < 8; ++j) E1[j] = (unsigned)__shfl_xor((int)D1[j], 32);
    union { unsigned u[4]; short8 s; } b0, b1;
    b0.u[0] = hi ? E1[2] : D1[0];  b0.u[1] = hi ? E1[3] : D1[1];
    b0.u[2] = hi ? D1[2] : E1[0];  b0.u[3] = hi ? D1[3] : E1[1];
    b1.u[0] = hi ? E1[6] : D1[4];  b1.u[1] = hi ? E1[7] : D1[5];
    b1.u[2] = hi ? D1[6] : E1[4];  b1.u[3] = hi ? D1[7] : E1[5];
    acc10 = __builtin_amdgcn_mfma_f32_32x32x16_bf16(b0.s, vb00, acc10, 0, 0, 0);
    acc11 = __builtin_amdgcn_mfma_f32_32x32x16_bf16(b0.s, vb01, acc11, 0, 0, 0);
    acc10 = __builtin_amdgcn_mfma_f32_32x32x16_bf16(b1.s, vb10, acc10, 0, 0, 0);
    acc11 = __builtin_amdgcn_mfma_f32_32x32x16_bf16(b1.s, vb11, acc11, 0, 0, 0);

    kf = kfn;
  }

  // combine the 8 key-splits (linear: no-max softmax)
  atomicAdd(&sLds[lo], psum0);
  atomicAdd(&sLds[32 + lo], psum1);
#pragma unroll
  for (int r = 0; r < 16; ++r) {
    const int q = (r & 3) + 8 * (r >> 2) + 4 * hi;   // D-layout row
    atomicAdd(&accLds[q][lo],           acc00[r]);
    atomicAdd(&accLds[q][32 + lo],      acc01[r]);
    atomicAdd(&accLds[32 + q][lo],      acc10[r]);
    atomicAdd(&accLds[32 + q][32 + lo], acc11[r]);
  }
  __syncthreads();

  // epilogue: out = gamma * (acc/s) + x ; lanes -> consecutive q (coalesced)
  const float g = gamma[0];
  const int qq = tid & 63;
  const int eb = tid >> 6;
  const float sinv = 1.0f / sLds[qq];
#pragma unroll
  for (int k = 0; k < 8; ++k) {
    const int e = eb + k * 8;
    const size_t idx = ((size_t)(b * 64 + e) << 12) + q0 + qq;
    out[idx] = fmaf(g, accLds[qq][e] * sinv, x[idx]);
  }
}

extern "C" void kernel_launch(void* const* d_in, const int* in_sizes, int n_in,
                              void* d_out, int out_size, void* d_ws, size_t ws_size,
                              hipStream_t stream) {
  const float* x     = (const float*)d_in[0];
  const float* Wq    = (const float*)d_in[1];
  const float* bq    = (const float*)d_in[2];
  const float* Wk    = (const float*)d_in[3];
  const float* bk    = (const float*)d_in[4];
  const float* Wv    = (const float*)d_in[5];
  const float* bv    = (const float*)d_in[6];
  const float* gamma = (const float*)d_in[7];
  float* out = (float*)d_out;

  short* ws = (short*)d_ws;
  short* Qp = ws;                 // 131072 shorts
  short* Kp = ws + 131072;        // 131072 shorts
  short* Vt = ws + 262144;        // 1048576 shorts

  proj_kernel<<<256, 320, 0, stream>>>(x, Wq, bq, Wk, bk, Wv, bv, Qp, Kp, Vt);
  attn_kernel<<<256, 512, 0, stream>>>(Qp, Kp, Vt, x, gamma, out);
}

// Round 3
// 134.300 us; speedup vs baseline: 2.0008x; 1.1721x over previous
//
#include <hip/hip_runtime.h>
#include <hip/hip_bf16.h>

#define NPIX 4096

typedef __attribute__((ext_vector_type(16))) float f32x16;
typedef __attribute__((ext_vector_type(8))) short short8;

__device__ inline short f2bf(float f) {   // round-to-nearest-even
  unsigned u = __float_as_uint(f);
  u += 0x7FFF + ((u >> 16) & 1);
  return (short)(u >> 16);
}

// ---------------- projection ----------------
// grid = 10 jobs x 64 pixel-blocks; block = 256 threads (thread = 1 pixel, 8 outputs)
// job 0: Q rows 0-7 (scaled by log2e) -> Qp[B*N][8]
// job 1: K rows 0-7                   -> Kp[B*N][8]
// jobs 2-9: V rows 8*(job-2)..+8      -> Vi[b][oct][e][ko]  (oct=n>>3, ko=n&7)
__global__ __launch_bounds__(256) void proj_kernel(
    const float* __restrict__ x,
    const float* __restrict__ Wq, const float* __restrict__ bq,
    const float* __restrict__ Wk, const float* __restrict__ bk,
    const float* __restrict__ Wv, const float* __restrict__ bv,
    short* __restrict__ Qp, short* __restrict__ Kp, short* __restrict__ Vi)
{
  const int job = blockIdx.x >> 6;
  const int p = (blockIdx.x & 63) * 256 + threadIdx.x;   // 0..16383
  const int b = p >> 12, n = p & 4095;
  const float* xb = x + ((size_t)b << 18) + n;

  float xv[64];
#pragma unroll
  for (int c = 0; c < 64; ++c) xv[c] = xb[(size_t)c << 12];

  if (job < 2) {
    const float* W    = job ? Wk : Wq;
    const float* bias = job ? bk : bq;
    float a[8];
#pragma unroll
    for (int d = 0; d < 8; ++d) {
      float acc = bias[d];
#pragma unroll
      for (int c = 0; c < 64; ++c) acc = fmaf(W[d * 64 + c], xv[c], acc);
      a[d] = acc;
    }
    short8 o;
    if (job == 0) {
#pragma unroll
      for (int d = 0; d < 8; ++d) o[d] = f2bf(a[d] * 1.44269504f);  // fold log2(e)
      *(short8*)(Qp + (size_t)p * 8) = o;
    } else {
#pragma unroll
      for (int d = 0; d < 8; ++d) o[d] = f2bf(a[d]);
      *(short8*)(Kp + (size_t)p * 8) = o;
    }
  } else {
    const int e0 = (job - 2) * 8;
    const size_t base = ((size_t)(b * 512 + (n >> 3)) * 64) * 8 + (n & 7);
#pragma unroll
    for (int i = 0; i < 8; ++i) {
      float acc = bv[e0 + i];
#pragma unroll
      for (int c = 0; c < 64; ++c) acc = fmaf(Wv[(e0 + i) * 64 + c], xv[c], acc);
      Vi[base + (size_t)(e0 + i) * 8] = f2bf(acc);
    }
  }
}

// pack 16 f32 softmax weights (D-layout regs of one q-half, one 32-key tile)
// into two PV A-fragments via cvt_pk + permlane32_swap (T12).
__device__ inline void pk_swap(const float* p, short8& A0, short8& A1) {
  unsigned u[8];
#pragma unroll
  for (int j = 0; j < 8; ++j)
    asm("v_cvt_pk_bf16_f32 %0, %1, %2" : "=v"(u[j]) : "v"(p[2 * j]), "v"(p[2 * j + 1]));
  // chunk0 (keys 0..15): words u0..u3 ; chunk1 (keys 16..31): u4..u7
  asm("v_permlane32_swap_b32 %0, %1" : "+v"(u[0]), "+v"(u[2]));
  asm("v_permlane32_swap_b32 %0, %1" : "+v"(u[1]), "+v"(u[3]));
  asm("v_permlane32_swap_b32 %0, %1" : "+v"(u[4]), "+v"(u[6]));
  asm("v_permlane32_swap_b32 %0, %1" : "+v"(u[5]), "+v"(u[7]));
  union { unsigned w[4]; short8 s; } c0, c1;
  c0.w[0] = u[0]; c0.w[1] = u[1]; c0.w[2] = u[2]; c0.w[3] = u[3];
  c1.w[0] = u[4]; c1.w[1] = u[5]; c1.w[2] = u[6]; c1.w[3] = u[7];
  A0 = c0.s; A1 = c1.s;
}

// ---------------- fused attention, no-max exp2 softmax ----------------
// grid = 256 (4 b x 64 q-groups of 64). 8 waves; wave wv = keys [wv*512, +512).
__global__ __launch_bounds__(512) void attn_kernel(
    const short* __restrict__ Qp, const short* __restrict__ Kp,
    const short* __restrict__ Vi,
    const float* __restrict__ x, const float* __restrict__ gamma,
    float* __restrict__ out)
{
  __shared__ float accLds[64][65];
  __shared__ float sLds[64];

  const int tid  = threadIdx.x;
  const int wv   = tid >> 6;
  const int lane = tid & 63;
  const int lo   = lane & 31;
  const int hi   = lane >> 5;

  const int b  = blockIdx.x >> 6;
  const int q0 = (blockIdx.x & 63) * 64;

  for (int i = tid; i < 64 * 65; i += 512) (&accLds[0][0])[i] = 0.f;
  if (tid < 64) sLds[tid] = 0.f;
  __syncthreads();

  // Q B-fragments: col=q=lo, k = channels (hi=1 half zero-padded)
  short8 qf0 = {}, qf1 = {};
  if (hi == 0) {
    qf0 = *(const short8*)(Qp + (size_t)((b << 12) + q0 + lo) * 8);
    qf1 = *(const short8*)(Qp + (size_t)((b << 12) + q0 + 32 + lo) * 8);
  }

  const short* kbase = Kp + ((size_t)b << 12) * 8;
  const short* vtb   = Vi + (size_t)b * 262144;   // 512 oct * 64 e * 8
  const int kb0 = wv * 512;

  auto loadK = [&](int kb) {
    return *(const short8*)(kbase + (size_t)(kb + lo) * 8);
  };
  auto loadV = [&](int kb, int c, int et) {   // coalesced: 2x512B segments
    const int oct = (kb >> 3) + 2 * c + hi;
    return *(const short8*)(vtb + ((size_t)oct * 64 + 32 * et + lo) * 8);
  };

  short8 kf  = loadK(kb0);
  short8 v00 = loadV(kb0, 0, 0), v01 = loadV(kb0, 0, 1);
  short8 v10 = loadV(kb0, 1, 0), v11 = loadV(kb0, 1, 1);

  f32x16 acc00 = {}, acc01 = {}, acc10 = {}, acc11 = {};
  float psum0 = 0.f, psum1 = 0.f;
  int kb = kb0;

#pragma unroll 2
  for (int t = 0; t < 16; ++t) {
    const int kbn = (t < 15) ? kb + 32 : kb0;       // wrap: stays in-bounds
    short8 kfn = loadK(kbn);
    short8 n00 = loadV(kbn, 0, 0), n01 = loadV(kbn, 0, 1);
    short8 n10 = loadV(kbn, 1, 0), n11 = loadV(kbn, 1, 1);

    const f32x16 z = {};
    __builtin_amdgcn_s_setprio(1);
    f32x16 en0 = __builtin_amdgcn_mfma_f32_32x32x16_bf16(kf, qf0, z, 0, 0, 0);
    f32x16 en1 = __builtin_amdgcn_mfma_f32_32x32x16_bf16(kf, qf1, z, 0, 0, 0);
    __builtin_amdgcn_s_setprio(0);

    // ---- q-half 0 ----
    float p0[16];
#pragma unroll
    for (int i = 0; i < 16; ++i) p0[i] = __builtin_amdgcn_exp2f(en0[i]);
#pragma unroll
    for (int i = 0; i < 16; ++i) psum0 += p0[i];
    short8 a0, a1;
    pk_swap(p0, a0, a1);
    __builtin_amdgcn_s_setprio(1);
    acc00 = __builtin_amdgcn_mfma_f32_32x32x16_bf16(a0, v00, acc00, 0, 0, 0);
    acc01 = __builtin_amdgcn_mfma_f32_32x32x16_bf16(a0, v01, acc01, 0, 0, 0);
    acc00 = __builtin_amdgcn_mfma_f32_32x32x16_bf16(a1, v10, acc00, 0, 0, 0);
    acc01 = __builtin_amdgcn_mfma_f32_32x32x16_bf16(a1, v11, acc01, 0, 0, 0);
    __builtin_amdgcn_s_setprio(0);

    // ---- q-half 1 ----
    float p1[16];
#pragma unroll
    for (int i = 0; i < 16; ++i) p1[i] = __builtin_amdgcn_exp2f(en1[i]);
#pragma unroll
    for (int i = 0; i < 16; ++i) psum1 += p1[i];
    short8 b0, b1;
    pk_swap(p1, b0, b1);
    __builtin_amdgcn_s_setprio(1);
    acc10 = __builtin_amdgcn_mfma_f32_32x32x16_bf16(b0, v00, acc10, 0, 0, 0);
    acc11 = __builtin_amdgcn_mfma_f32_32x32x16_bf16(b0, v01, acc11, 0, 0, 0);
    acc10 = __builtin_amdgcn_mfma_f32_32x32x16_bf16(b1, v10, acc10, 0, 0, 0);
    acc11 = __builtin_amdgcn_mfma_f32_32x32x16_bf16(b1, v11, acc11, 0, 0, 0);
    __builtin_amdgcn_s_setprio(0);

    kf = kfn; v00 = n00; v01 = n01; v10 = n10; v11 = n11; kb = kbn;
  }

  // combine 8 key-splits (linear: no-max softmax)
  atomicAdd(&sLds[lo], psum0);
  atomicAdd(&sLds[32 + lo], psum1);
#pragma unroll
  for (int r = 0; r < 16; ++r) {
    const int q = (r & 3) + 8 * (r >> 2) + 4 * hi;
    atomicAdd(&accLds[q][lo],           acc00[r]);
    atomicAdd(&accLds[q][32 + lo],      acc01[r]);
    atomicAdd(&accLds[32 + q][lo],      acc10[r]);
    atomicAdd(&accLds[32 + q][32 + lo], acc11[r]);
  }
  __syncthreads();

  // out = gamma * (acc/s) + x
  const float g = gamma[0];
  const int qq = tid & 63;
  const int eb = tid >> 6;
  const float sinv = 1.0f / sLds[qq];
#pragma unroll
  for (int k = 0; k < 8; ++k) {
    const int e = eb + k * 8;
    const size_t idx = ((size_t)(b * 64 + e) << 12) + q0 + qq;
    out[idx] = fmaf(g, accLds[qq][e] * sinv, x[idx]);
  }
}

extern "C" void kernel_launch(void* const* d_in, const int* in_sizes, int n_in,
                              void* d_out, int out_size, void* d_ws, size_t ws_size,
                              hipStream_t stream) {
  const float* x     = (const float*)d_in[0];
  const float* Wq    = (const float*)d_in[1];
  const float* bq    = (const float*)d_in[2];
  const float* Wk    = (const float*)d_in[3];
  const float* bk    = (const float*)d_in[4];
  const float* Wv    = (const float*)d_in[5];
  const float* bv    = (const float*)d_in[6];
  const float* gamma = (const float*)d_in[7];
  float* out = (float*)d_out;

  short* ws = (short*)d_ws;
  short* Qp = ws;                 // 131072 shorts
  short* Kp = ws + 131072;        // 131072 shorts
  short* Vi = ws + 262144;        // 1048576 shorts: [4][512][64][8]

  proj_kernel<<<640, 256, 0, stream>>>(x, Wq, bq, Wk, bk, Wv, bv, Qp, Kp, Vi);
  attn_kernel<<<256, 512, 0, stream>>>(Qp, Kp, Vi, x, gamma, out);
}

// Round 4
// 131.794 us; speedup vs baseline: 2.0388x; 1.0190x over previous
//
#include <hip/hip_runtime.h>
#include <hip/hip_bf16.h>

#define NPIX 4096

typedef __attribute__((ext_vector_type(16))) float f32x16;
typedef __attribute__((ext_vector_type(8))) short short8;

__device__ inline short f2bf(float f) {   // round-to-nearest-even
  unsigned u = __float_as_uint(f);
  u += 0x7FFF + ((u >> 16) & 1);
  return (short)(u >> 16);
}

// ---------------- projection (unchanged from R3) ----------------
// grid = 10 jobs x 64 pixel-blocks; block = 256 threads (thread = 1 pixel, 8 outputs)
// job 0: Q rows 0-7 (scaled by log2e) -> Qp[B*N][8]
// job 1: K rows 0-7                   -> Kp[B*N][8]
// jobs 2-9: V rows 8*(job-2)..+8      -> Vi[b][oct][e][ko]  (oct=n>>3, ko=n&7)
__global__ __launch_bounds__(256) void proj_kernel(
    const float* __restrict__ x,
    const float* __restrict__ Wq, const float* __restrict__ bq,
    const float* __restrict__ Wk, const float* __restrict__ bk,
    const float* __restrict__ Wv, const float* __restrict__ bv,
    short* __restrict__ Qp, short* __restrict__ Kp, short* __restrict__ Vi)
{
  const int job = blockIdx.x >> 6;
  const int p = (blockIdx.x & 63) * 256 + threadIdx.x;   // 0..16383
  const int b = p >> 12, n = p & 4095;
  const float* xb = x + ((size_t)b << 18) + n;

  float xv[64];
#pragma unroll
  for (int c = 0; c < 64; ++c) xv[c] = xb[(size_t)c << 12];

  if (job < 2) {
    const float* W    = job ? Wk : Wq;
    const float* bias = job ? bk : bq;
    float a[8];
#pragma unroll
    for (int d = 0; d < 8; ++d) {
      float acc = bias[d];
#pragma unroll
      for (int c = 0; c < 64; ++c) acc = fmaf(W[d * 64 + c], xv[c], acc);
      a[d] = acc;
    }
    short8 o;
    if (job == 0) {
#pragma unroll
      for (int d = 0; d < 8; ++d) o[d] = f2bf(a[d] * 1.44269504f);  // fold log2(e)
      *(short8*)(Qp + (size_t)p * 8) = o;
    } else {
#pragma unroll
      for (int d = 0; d < 8; ++d) o[d] = f2bf(a[d]);
      *(short8*)(Kp + (size_t)p * 8) = o;
    }
  } else {
    const int e0 = (job - 2) * 8;
    const size_t base = ((size_t)(b * 512 + (n >> 3)) * 64) * 8 + (n & 7);
#pragma unroll
    for (int i = 0; i < 8; ++i) {
      float acc = bv[e0 + i];
#pragma unroll
      for (int c = 0; c < 64; ++c) acc = fmaf(Wv[(e0 + i) * 64 + c], xv[c], acc);
      Vi[base + (size_t)(e0 + i) * 8] = f2bf(acc);
    }
  }
}

// pack 16 f32 softmax weights (D-layout regs, one 32-key tile) into two PV
// A-fragments via cvt_pk + permlane32_swap (T12).
__device__ inline void pk_swap(const float* p, short8& A0, short8& A1) {
  unsigned u[8];
#pragma unroll
  for (int j = 0; j < 8; ++j)
    asm("v_cvt_pk_bf16_f32 %0, %1, %2" : "=v"(u[j]) : "v"(p[2 * j]), "v"(p[2 * j + 1]));
  asm("v_permlane32_swap_b32 %0, %1" : "+v"(u[0]), "+v"(u[2]));
  asm("v_permlane32_swap_b32 %0, %1" : "+v"(u[1]), "+v"(u[3]));
  asm("v_permlane32_swap_b32 %0, %1" : "+v"(u[4]), "+v"(u[6]));
  asm("v_permlane32_swap_b32 %0, %1" : "+v"(u[5]), "+v"(u[7]));
  union { unsigned w[4]; short8 s; } c0, c1;
  c0.w[0] = u[0]; c0.w[1] = u[1]; c0.w[2] = u[2]; c0.w[3] = u[3];
  c1.w[0] = u[4]; c1.w[1] = u[5]; c1.w[2] = u[6]; c1.w[3] = u[7];
  A0 = c0.s; A1 = c1.s;
}

// ---------------- fused attention, no-max exp2 softmax ----------------
// grid = 512 blocks = 8 XCD-slots x 64; block = 8 waves.
// XCD-pinned: xcd = bid&7 -> batch = xcd>>1, so each XCD's L2 holds ONE
// batch's K/V/Q (~0.7 MB). Block: q-group of 32, wave wv = keys [wv*512,+512).
// Depth-2 software pipeline (named A/B stages), no LDS in main loop.
__global__ __launch_bounds__(512, 4) void attn_kernel(
    const short* __restrict__ Qp, const short* __restrict__ Kp,
    const short* __restrict__ Vi,
    const float* __restrict__ x, const float* __restrict__ gamma,
    float* __restrict__ out)
{
  __shared__ float accLds[32][65];
  __shared__ float sLds[32];

  const int tid  = threadIdx.x;
  const int wv   = tid >> 6;
  const int lane = tid & 63;
  const int lo   = lane & 31;
  const int hi   = lane >> 5;

  const int u   = blockIdx.x;
  const int xcd = u & 7;
  const int b   = xcd >> 1;
  const int q0  = (((xcd & 1) << 6) + (u >> 3)) * 32;   // 128 q-groups of 32

  for (int i = tid; i < 32 * 65; i += 512) (&accLds[0][0])[i] = 0.f;
  if (tid < 32) sLds[tid] = 0.f;
  __syncthreads();

  // Q B-fragment: col=q=lo, k=channels (hi half zero-padded)
  short8 qf = {};
  if (hi == 0) qf = *(const short8*)(Qp + (size_t)((b << 12) + q0 + lo) * 8);

  const short* kbase = Kp + ((size_t)b << 12) * 8;
  const short* vtb   = Vi + (size_t)b * 262144;   // 512 oct * 64 e * 8
  const int kb0 = wv * 512;

  auto loadK = [&](int kb) {
    return *(const short8*)(kbase + (size_t)(kb + lo) * 8);
  };
  auto loadV = [&](int kb, int c, int et) {   // coalesced: 2x512B segments
    const int oct = (kb >> 3) + 2 * c + hi;
    return *(const short8*)(vtb + ((size_t)oct * 64 + 32 * et + lo) * 8);
  };

  // prefetch stages A (t) and B (t+1)
  short8 kA  = loadK(kb0);
  short8 vA0 = loadV(kb0, 0, 0), vA1 = loadV(kb0, 0, 1);
  short8 vA2 = loadV(kb0, 1, 0), vA3 = loadV(kb0, 1, 1);
  short8 kB  = loadK(kb0 + 32);
  short8 vB0 = loadV(kb0 + 32, 0, 0), vB1 = loadV(kb0 + 32, 0, 1);
  short8 vB2 = loadV(kb0 + 32, 1, 0), vB3 = loadV(kb0 + 32, 1, 1);

  f32x16 acc0 = {}, acc1 = {};
  float psum = 0.f;
  const f32x16 z = {};

  for (int t = 0; t < 16; t += 2) {
    // ---- even body: consume stage A ----
    f32x16 en = __builtin_amdgcn_mfma_f32_32x32x16_bf16(kA, qf, z, 0, 0, 0);
    float p[16];
#pragma unroll
    for (int i = 0; i < 16; ++i) p[i] = __builtin_amdgcn_exp2f(en[i]);
#pragma unroll
    for (int i = 0; i < 16; ++i) psum += p[i];
    short8 a0, a1;
    pk_swap(p, a0, a1);
    __builtin_amdgcn_s_setprio(1);
    acc0 = __builtin_amdgcn_mfma_f32_32x32x16_bf16(a0, vA0, acc0, 0, 0, 0);
    acc1 = __builtin_amdgcn_mfma_f32_32x32x16_bf16(a0, vA1, acc1, 0, 0, 0);
    acc0 = __builtin_amdgcn_mfma_f32_32x32x16_bf16(a1, vA2, acc0, 0, 0, 0);
    acc1 = __builtin_amdgcn_mfma_f32_32x32x16_bf16(a1, vA3, acc1, 0, 0, 0);
    __builtin_amdgcn_s_setprio(0);
    {   // refill stage A for t+2 (wraps in-bounds at the tail; values unused)
      const int kn = kb0 + ((t + 2) & 15) * 32;
      kA  = loadK(kn);
      vA0 = loadV(kn, 0, 0); vA1 = loadV(kn, 0, 1);
      vA2 = loadV(kn, 1, 0); vA3 = loadV(kn, 1, 1);
    }

    // ---- odd body: consume stage B ----
    en = __builtin_amdgcn_mfma_f32_32x32x16_bf16(kB, qf, z, 0, 0, 0);
#pragma unroll
    for (int i = 0; i < 16; ++i) p[i] = __builtin_amdgcn_exp2f(en[i]);
#pragma unroll
    for (int i = 0; i < 16; ++i) psum += p[i];
    short8 b0, b1;
    pk_swap(p, b0, b1);
    __builtin_amdgcn_s_setprio(1);
    acc0 = __builtin_amdgcn_mfma_f32_32x32x16_bf16(b0, vB0, acc0, 0, 0, 0);
    acc1 = __builtin_amdgcn_mfma_f32_32x32x16_bf16(b0, vB1, acc1, 0, 0, 0);
    acc0 = __builtin_amdgcn_mfma_f32_32x32x16_bf16(b1, vB2, acc0, 0, 0, 0);
    acc1 = __builtin_amdgcn_mfma_f32_32x32x16_bf16(b1, vB3, acc1, 0, 0, 0);
    __builtin_amdgcn_s_setprio(0);
    {   // refill stage B for t+3
      const int kn = kb0 + ((t + 3) & 15) * 32;
      kB  = loadK(kn);
      vB0 = loadV(kn, 0, 0); vB1 = loadV(kn, 0, 1);
      vB2 = loadV(kn, 1, 0); vB3 = loadV(kn, 1, 1);
    }
  }

  // combine 8 key-splits (linear: no-max softmax)
  atomicAdd(&sLds[lo], psum);
#pragma unroll
  for (int r = 0; r < 16; ++r) {
    const int q = (r & 3) + 8 * (r >> 2) + 4 * hi;   // D-layout row
    atomicAdd(&accLds[q][lo],      acc0[r]);
    atomicAdd(&accLds[q][32 + lo], acc1[r]);
  }
  __syncthreads();

  // out = gamma * (acc/s) + x ; 2048 outputs, 4 per thread
  const float g = gamma[0];
  const int qq = tid & 31;
  const int e0 = tid >> 5;           // 0..15
  const float sinv = 1.0f / sLds[qq];
#pragma unroll
  for (int k = 0; k < 4; ++k) {
    const int e = e0 + k * 16;
    const size_t idx = ((size_t)(b * 64 + e) << 12) + q0 + qq;
    out[idx] = fmaf(g, accLds[qq][e] * sinv, x[idx]);
  }
}

extern "C" void kernel_launch(void* const* d_in, const int* in_sizes, int n_in,
                              void* d_out, int out_size, void* d_ws, size_t ws_size,
                              hipStream_t stream) {
  const float* x     = (const float*)d_in[0];
  const float* Wq    = (const float*)d_in[1];
  const float* bq    = (const float*)d_in[2];
  const float* Wk    = (const float*)d_in[3];
  const float* bk    = (const float*)d_in[4];
  const float* Wv    = (const float*)d_in[5];
  const float* bv    = (const float*)d_in[6];
  const float* gamma = (const float*)d_in[7];
  float* out = (float*)d_out;

  short* ws = (short*)d_ws;
  short* Qp = ws;                 // 131072 shorts
  short* Kp = ws + 131072;        // 131072 shorts
  short* Vi = ws + 262144;        // 1048576 shorts: [4][512][64][8]

  proj_kernel<<<640, 256, 0, stream>>>(x, Wq, bq, Wk, bk, Wv, bv, Qp, Kp, Vi);
  attn_kernel<<<512, 512, 0, stream>>>(Qp, Kp, Vi, x, gamma, out);
}

// Round 5
// 104.905 us; speedup vs baseline: 2.5614x; 1.2563x over previous
//
#include <hip/hip_runtime.h>
#include <hip/hip_bf16.h>

#define NPIX 4096

typedef __attribute__((ext_vector_type(16))) float f32x16;
typedef __attribute__((ext_vector_type(8))) short short8;

__device__ inline short f2bf(float f) {   // round-to-nearest-even
  unsigned u = __float_as_uint(f);
  u += 0x7FFF + ((u >> 16) & 1);
  return (short)(u >> 16);
}

__device__ inline void gload16(const short* g, short* l) {
  __builtin_amdgcn_global_load_lds(
      (const __attribute__((address_space(1))) void*)g,
      (__attribute__((address_space(3))) void*)l, 16, 0, 0);
}

// ---------------- projection (unchanged since R3) ----------------
// job 0: Q rows (xlog2e) -> Qp[B*N][8]; job 1: K -> Kp[B*N][8];
// jobs 2-9: V -> Vi[b][oct][e][ko]  (oct=n>>3, ko=n&7)
__global__ __launch_bounds__(256) void proj_kernel(
    const float* __restrict__ x,
    const float* __restrict__ Wq, const float* __restrict__ bq,
    const float* __restrict__ Wk, const float* __restrict__ bk,
    const float* __restrict__ Wv, const float* __restrict__ bv,
    short* __restrict__ Qp, short* __restrict__ Kp, short* __restrict__ Vi)
{
  const int job = blockIdx.x >> 6;
  const int p = (blockIdx.x & 63) * 256 + threadIdx.x;
  const int b = p >> 12, n = p & 4095;
  const float* xb = x + ((size_t)b << 18) + n;

  float xv[64];
#pragma unroll
  for (int c = 0; c < 64; ++c) xv[c] = xb[(size_t)c << 12];

  if (job < 2) {
    const float* W    = job ? Wk : Wq;
    const float* bias = job ? bk : bq;
    float a[8];
#pragma unroll
    for (int d = 0; d < 8; ++d) {
      float acc = bias[d];
#pragma unroll
      for (int c = 0; c < 64; ++c) acc = fmaf(W[d * 64 + c], xv[c], acc);
      a[d] = acc;
    }
    short8 o;
    if (job == 0) {
#pragma unroll
      for (int d = 0; d < 8; ++d) o[d] = f2bf(a[d] * 1.44269504f);
      *(short8*)(Qp + (size_t)p * 8) = o;
    } else {
#pragma unroll
      for (int d = 0; d < 8; ++d) o[d] = f2bf(a[d]);
      *(short8*)(Kp + (size_t)p * 8) = o;
    }
  } else {
    const int e0 = (job - 2) * 8;
    const size_t base = ((size_t)(b * 512 + (n >> 3)) * 64) * 8 + (n & 7);
#pragma unroll
    for (int i = 0; i < 8; ++i) {
      float acc = bv[e0 + i];
#pragma unroll
      for (int c = 0; c < 64; ++c) acc = fmaf(Wv[(e0 + i) * 64 + c], xv[c], acc);
      Vi[base + (size_t)(e0 + i) * 8] = f2bf(acc);
    }
  }
}

// T12 pack: 16 f32 weights -> two PV A-fragments (cvt_pk + permlane32_swap)
__device__ inline void pk_swap(const float* p, short8& A0, short8& A1) {
  unsigned u[8];
#pragma unroll
  for (int j = 0; j < 8; ++j)
    asm("v_cvt_pk_bf16_f32 %0, %1, %2" : "=v"(u[j]) : "v"(p[2 * j]), "v"(p[2 * j + 1]));
  asm("v_permlane32_swap_b32 %0, %1" : "+v"(u[0]), "+v"(u[2]));
  asm("v_permlane32_swap_b32 %0, %1" : "+v"(u[1]), "+v"(u[3]));
  asm("v_permlane32_swap_b32 %0, %1" : "+v"(u[4]), "+v"(u[6]));
  asm("v_permlane32_swap_b32 %0, %1" : "+v"(u[5]), "+v"(u[7]));
  union { unsigned w[4]; short8 s; } c0, c1;
  c0.w[0] = u[0]; c0.w[1] = u[1]; c0.w[2] = u[2]; c0.w[3] = u[3];
  c1.w[0] = u[4]; c1.w[1] = u[5]; c1.w[2] = u[6]; c1.w[3] = u[7];
  A0 = c0.s; A1 = c1.s;
}

// ---------------- attention pass 1: LDS-shared tiles, q-split waves ----------------
// grid 256 = (4 b) x (16 qg) x (4 ks). block = 8 waves; wave wv owns q-tile
// [qg*256 + wv*32, +32), keys [ks*1024, +1024) in 8 chunks of 128 keys,
// double-buffered LDS staged via global_load_lds (all 8 waves share the tile).
// Partial O (bf16) and psum (f32) written to ws; no atomics.
__global__ __launch_bounds__(512, 2) void attn_kernel(
    const short* __restrict__ Qp, const short* __restrict__ Kp,
    const short* __restrict__ Vi,
    short* __restrict__ accB, float* __restrict__ psumW)
{
  __shared__ short kLds[2][1024];        // [dbuf][128 keys][8 ch]    2x2 KB
  __shared__ short vLds[2][8192];        // [dbuf][16 oct][64 e][8 k] 2x16 KB

  const int tid  = threadIdx.x;
  const int wv   = tid >> 6;
  const int lane = tid & 63;
  const int lo   = lane & 31;
  const int hi   = lane >> 5;

  const int bid = blockIdx.x;
  const int ks  = bid & 3;
  const int qg  = (bid >> 2) & 15;
  const int b   = bid >> 6;
  const int Qgbase = (b << 12) + qg * 256 + wv * 32;   // global q index base

  short8 qf = {};
  if (hi == 0) qf = *(const short8*)(Qp + (size_t)(Qgbase + lo) * 8);

  const short* ksrc = Kp + ((size_t)(b << 12) + ks * 1024) * 8;   // 128 keys/chunk = 1024 shorts
  const short* vsrc = Vi + (size_t)b * 262144 + (size_t)ks * 65536; // 128 keys = 8192 shorts

  auto stage = [&](int c, int buf) {
    const short* vs = vsrc + (size_t)c * 8192;
    // V: 1024 x 16B ops, linear; LDS dest = wave-uniform base (+lane*16 in HW)
    gload16(vs + (size_t)tid * 8,         &vLds[buf][(tid & ~63) * 8]);
    gload16(vs + (size_t)(tid + 512) * 8, &vLds[buf][((tid + 512) & ~63) * 8]);
    if (tid < 128)   // waves 0,1 fully active
      gload16(ksrc + (size_t)c * 1024 + (size_t)tid * 8, &kLds[buf][(tid & ~63) * 8]);
  };

  f32x16 acc0 = {}, acc1 = {};
  float psum = 0.f;
  const f32x16 z = {};

  stage(0, 0);
  __syncthreads();

  for (int c = 0; c < 8; ++c) {
    if (c < 7) stage(c + 1, (c + 1) & 1);
    const int buf = c & 1;
#pragma unroll
    for (int i = 0; i < 4; ++i) {
      short8 kf = *(const short8*)&kLds[buf][(i * 32 + lo) * 8];
      f32x16 en = __builtin_amdgcn_mfma_f32_32x32x16_bf16(kf, qf, z, 0, 0, 0);
      float p[16];
#pragma unroll
      for (int j = 0; j < 16; ++j) p[j] = __builtin_amdgcn_exp2f(en[j]);
#pragma unroll
      for (int j = 0; j < 16; ++j) psum += p[j];
      short8 a0, a1;
      pk_swap(p, a0, a1);
      short8 v00 = *(const short8*)&vLds[buf][(i * 4 + hi) * 512 + lo * 8];
      short8 v01 = *(const short8*)&vLds[buf][(i * 4 + hi) * 512 + (32 + lo) * 8];
      short8 v10 = *(const short8*)&vLds[buf][(i * 4 + 2 + hi) * 512 + lo * 8];
      short8 v11 = *(const short8*)&vLds[buf][(i * 4 + 2 + hi) * 512 + (32 + lo) * 8];
      __builtin_amdgcn_s_setprio(1);
      acc0 = __builtin_amdgcn_mfma_f32_32x32x16_bf16(a0, v00, acc0, 0, 0, 0);
      acc1 = __builtin_amdgcn_mfma_f32_32x32x16_bf16(a0, v01, acc1, 0, 0, 0);
      acc0 = __builtin_amdgcn_mfma_f32_32x32x16_bf16(a1, v10, acc0, 0, 0, 0);
      acc1 = __builtin_amdgcn_mfma_f32_32x32x16_bf16(a1, v11, acc1, 0, 0, 0);
      __builtin_amdgcn_s_setprio(0);
    }
    __syncthreads();   // drains vmcnt (stage) + readers done before overwrite
  }

  // partial psum: combine hi halves, store per q (coalesced 128B)
  float pfull = psum + __shfl_xor(psum, 32);
  if (hi == 0) psumW[ks * 16384 + Qgbase + lo] = pfull;

  // partial O: bf16, rows = q, cols = e (lane lo -> e)
#pragma unroll
  for (int r = 0; r < 16; ++r) {
    const int q = (r & 3) + 8 * (r >> 2) + 4 * hi;
    const size_t base = ((size_t)(ks * 16384 + Qgbase + q)) << 6;
    accB[base + lo]      = f2bf(acc0[r]);
    accB[base + 32 + lo] = f2bf(acc1[r]);
  }
}

// ---------------- attention pass 2: combine 4 key-splits + epilogue ----------------
// grid 256 x 256 thr; block handles 64 consecutive global q.
__global__ __launch_bounds__(256) void reduce_kernel(
    const short* __restrict__ accB, const float* __restrict__ psumW,
    const float* __restrict__ x, const float* __restrict__ gamma,
    float* __restrict__ out)
{
  __shared__ float accLds[64][65];
  __shared__ float sInv[64];

  const int tid = threadIdx.x;
  const int Qg0 = blockIdx.x * 64;
  const float g = gamma[0];

  if (tid < 64) {
    float s = 0.f;
#pragma unroll
    for (int ks = 0; ks < 4; ++ks) s += psumW[ks * 16384 + Qg0 + tid];
    sInv[tid] = g / s;
  }

  const int e2 = tid & 31;          // e-pair index
  const int qr = tid >> 5;          // 8 q-rows per sweep
#pragma unroll
  for (int qs = 0; qs < 8; ++qs) {
    const int qq = qr + qs * 8;
    float s0 = 0.f, s1 = 0.f;
#pragma unroll
    for (int ks = 0; ks < 4; ++ks) {
      const unsigned u = *(const unsigned*)&accB[(((size_t)(ks * 16384 + Qg0 + qq)) << 6) + e2 * 2];
      s0 += __uint_as_float(u << 16);
      s1 += __uint_as_float(u & 0xFFFF0000u);
    }
    accLds[qq][e2 * 2]     = s0;
    accLds[qq][e2 * 2 + 1] = s1;
  }
  __syncthreads();

  const int q  = tid & 63;
  const int er = tid >> 6;
  const int b  = (Qg0 + q) >> 12;
  const int n  = (Qg0 + q) & 4095;
  const float si = sInv[q];
#pragma unroll
  for (int k = 0; k < 16; ++k) {
    const int e = er + k * 4;
    const size_t idx = ((size_t)(b * 64 + e) << 12) + n;
    out[idx] = fmaf(si, accLds[q][e], x[idx]);
  }
}

extern "C" void kernel_launch(void* const* d_in, const int* in_sizes, int n_in,
                              void* d_out, int out_size, void* d_ws, size_t ws_size,
                              hipStream_t stream) {
  const float* x     = (const float*)d_in[0];
  const float* Wq    = (const float*)d_in[1];
  const float* bq    = (const float*)d_in[2];
  const float* Wk    = (const float*)d_in[3];
  const float* bk    = (const float*)d_in[4];
  const float* Wv    = (const float*)d_in[5];
  const float* bv    = (const float*)d_in[6];
  const float* gamma = (const float*)d_in[7];
  float* out = (float*)d_out;

  short* ws   = (short*)d_ws;
  short* Qp   = ws;                       // 131072 shorts
  short* Kp   = ws + 131072;              // 131072 shorts
  short* Vi   = ws + 262144;              // 1048576 shorts: [4][512][64][8]
  short* accB = ws + 1310720;             // 4*16384*64 = 4194304 shorts (8 MB)
  float* psumW = (float*)(ws + 5505024);  // 65536 floats (256 KB)

  proj_kernel<<<640, 256, 0, stream>>>(x, Wq, bq, Wk, bk, Wv, bv, Qp, Kp, Vi);
  attn_kernel<<<256, 512, 0, stream>>>(Qp, Kp, Vi, accB, psumW);
  reduce_kernel<<<256, 256, 0, stream>>>(accB, psumW, x, gamma, out);
}